// Round 8
// baseline (256.546 us; speedup 1.0000x reference)
//
#include <hip/hip_runtime.h>
#include <stdint.h>

// Problem constants
#define L_SEQ   900000          // 3000 words * 300 dims
#define N_WORDS 3000
#define WDIM    300
#define NB      4               // batch
#define NFPAD   320             // filters padded to 20 MFMA tiles of 16
#define NT      256             // threads per block (4 waves; wave w owns tiles 5w..5w+4)
#define STRIP   2048            // positions per block = 128 steps of 16
#define STEPS   128
#define NSTRIPS 440             // ceil(899968/2048); last strip partial (56 steps)
#define L_MAIN  899968          // main MFMA path covers t in [0, L_MAIN); tail covers the rest
#define NPP     900016          // packed plane entries per batch (L_MAIN + 48 pad)

typedef __attribute__((ext_vector_type(8))) short    bf16x8;
typedef __attribute__((ext_vector_type(4))) float    f32x4;
typedef __attribute__((ext_vector_type(4))) unsigned u32x4v;

__device__ __forceinline__ unsigned bf16rne(float v) {
    unsigned b = __float_as_uint(v);
    return (b + 0x7FFFu + ((b >> 16) & 1u)) >> 16;   // bf16 RNE, as ushort
}
// order-preserving float -> uint key (atomicMax-able, handles negatives)
__device__ __forceinline__ unsigned monokey(float v) {
    unsigned u = __float_as_uint(v);
    return u ^ (unsigned)(((int)u >> 31) | 0x80000000);
}
// pack two f32 -> {bf16(a) lo16, bf16(b) hi16} (RNE) — no builtin on gfx950
__device__ __forceinline__ unsigned cvt_pk_bf16(float a, float b) {
    unsigned r;
    asm("v_cvt_pk_bf16_f32 %0, %1, %2" : "=v"(r) : "v"(a), "v"(b));
    return r;
}

__device__ __forceinline__ float gatherE(const int* __restrict__ x,
                                         const float* __restrict__ emb,
                                         int b, int pos) {
    if (pos >= L_SEQ) return 0.f;
    int wd = pos / WDIM;                  // constant divisor -> magic mul
    int d  = pos - wd * WDIM;
    return emb[x[b * N_WORDS + wd] * WDIM + d];
}

// ---------------------------------------------------------------------------
// pack_kernel: one pass over all positions. For each (b, p):
//   uEhi[b][p] = {trunc16(E[p]), trunc16(E[p+1])}          (u32 pair)
//   uElo[b][p] = {bf16rne(E[p]-hi), bf16rne(E[p+1]-hi)}    (u32 pair)
// Also stages the W hi/lo split table (5120 ushort) and zeroes maxkey.
// grid (3516, NB) x 256.
// ---------------------------------------------------------------------------
__global__ __launch_bounds__(NT) void pack_kernel(
    const int*   __restrict__ x,    // [4,3000]
    const float* __restrict__ emb,  // [VOCAB,300]
    const float* __restrict__ w1, const float* __restrict__ w2, const float* __restrict__ w3,
    unsigned*       __restrict__ uEhi,    // [NB][NPP]
    unsigned*       __restrict__ uElo,    // [NB][NPP]
    unsigned short* __restrict__ wsplit,  // [2][2560]
    unsigned*       __restrict__ maxkey)  // [NB*NFPAD]
{
    const int tid = threadIdx.x;
    const int b   = blockIdx.y;
    const int p   = blockIdx.x * NT + tid;

    if (p < NPP) {
        float v0 = gatherE(x, emb, b, p);
        float v1 = gatherE(x, emb, b, p + 1);
        unsigned u0 = __float_as_uint(v0), u1 = __float_as_uint(v1);
        float l0 = v0 - __uint_as_float(u0 & 0xFFFF0000u);
        float l1 = v1 - __uint_as_float(u1 & 0xFFFF0000u);
        uEhi[b * NPP + p] = __builtin_amdgcn_perm(u1, u0, 0x07060302u); // {hi0, hi1}
        uElo[b * NPP + p] = cvt_pk_bf16(l0, l1);                        // {lo0, lo1}
    }

    if (blockIdx.y == 0 && blockIdx.x < 10) {
        int widx = blockIdx.x * NT + tid;       // 0..2559
        int f = widx >> 3, j = widx & 7;
        float wv = 0.f;
        if (f < 100)      { if (j < 3) wv = w1[f * 3 + j]; }
        else if (f < 200) { if (j < 4) wv = w2[(f - 100) * 4 + j]; }
        else if (f < 300) { if (j < 5) wv = w3[(f - 200) * 5 + j]; }
        unsigned rh = bf16rne(wv);
        float lo = wv - __uint_as_float(rh << 16);
        wsplit[widx]        = (unsigned short)rh;
        wsplit[2560 + widx] = (unsigned short)bf16rne(lo);
        if (widx < NB * NFPAD) maxkey[widx] = 0u;
    }
}

// ---------------------------------------------------------------------------
// conv_mfma_kernel: NO LDS, NO barriers in the main path. Per 16-pos step:
//   one mfma_f32_16x16x32_bf16 per 16-filter tile (5 tiles/wave, 4 waves):
//   A quarters (k-groups) = {Whi, Wlo, Whi, Wlo}
//   B quarters            = {Ehi, Ehi, Elo, Elo}   (full 4-term split product)
// B comes straight from the packed global planes (L1-broadcast across waves),
// prefetched one iteration ahead. grid (NSTRIPS+1, NB), block 256.
// Block bx==NSTRIPS does the exact-fp32 tail for t in [L_MAIN, L_SEQ-K].
// ---------------------------------------------------------------------------
__global__ __launch_bounds__(NT) void conv_mfma_kernel(
    const int*   __restrict__ x,    // for tail only
    const float* __restrict__ emb,  // for tail only
    const float* __restrict__ w1, const float* __restrict__ w2, const float* __restrict__ w3,
    const unsigned*       __restrict__ uEhi,
    const unsigned*       __restrict__ uElo,
    const unsigned short* __restrict__ wsplit,
    unsigned*    __restrict__ maxkey)
{
    __shared__ float tE[48];            // used only by the tail block

    const int tid = threadIdx.x;
    const int b   = blockIdx.y;
    const int bx  = blockIdx.x;

    if (bx == NSTRIPS) {
        // ---------------- exact fp32 tail: t in [L_MAIN, L_SEQ-K] ----------------
        if (tid < 48) tE[tid] = gatherE(x, emb, b, L_MAIN + tid);
        __syncthreads();
        for (int f = tid; f < 300; f += NT) {
            int K; const float* wp;
            if (f < 100)      { K = 3; wp = w1 + f * 3; }
            else if (f < 200) { K = 4; wp = w2 + (f - 100) * 4; }
            else              { K = 5; wp = w3 + (f - 200) * 5; }
            float wk0 = wp[0], wk1 = wp[1], wk2 = (K > 2) ? wp[2] : 0.f;
            float wk3 = (K > 3) ? wp[3] : 0.f, wk4 = (K > 4) ? wp[4] : 0.f;
            float m = -1e30f;
            int tmax = L_SEQ - K;
            for (int t = L_MAIN; t <= tmax; ++t) {
                int o = t - L_MAIN;
                float y = wk0 * tE[o] + wk1 * tE[o + 1] + wk2 * tE[o + 2]
                        + wk3 * tE[o + 3] + wk4 * tE[o + 4];
                m = fmaxf(m, y);
            }
            atomicMax(&maxkey[b * NFPAD + f], monokey(m));
        }
        return;
    }

    const int strip0 = bx * STRIP;
    const int lane = tid & 63;
    const int wid  = tid >> 6;           // wave 0..3
    const int col  = lane & 15;
    const int q    = lane >> 4;          // k-group 0..3
    const int part = q & 1;

    // ---- A fragments: 5 tiles/wave, straight from global (16B aligned) ----
    const unsigned short* wb = wsplit + part * 2560 + ((5 * wid) * 16 + col) * 8;
    bf16x8 aw0 = *(const bf16x8*)(const void*)(wb + 0 * 128);
    bf16x8 aw1 = *(const bf16x8*)(const void*)(wb + 1 * 128);
    bf16x8 aw2 = *(const bf16x8*)(const void*)(wb + 2 * 128);
    bf16x8 aw3 = *(const bf16x8*)(const void*)(wb + 3 * 128);
    bf16x8 aw4 = *(const bf16x8*)(const void*)(wb + 4 * 128);

    int nsteps = (L_MAIN - strip0) / 16;     // 128, or 56 for the last strip — even
    if (nsteps > STEPS) nsteps = STEPS;

    const f32x4 Z = {0.f, 0.f, 0.f, 0.f};
    f32x4 rm0 = {-1e30f,-1e30f,-1e30f,-1e30f}, rm1 = rm0, rm2 = rm0, rm3 = rm0, rm4 = rm0;

    // B source: lanes 0-31 read hi plane, 32-63 read lo plane (quarters {hi,hi,lo,lo})
    const unsigned* bp = ((lane >> 5) ? uElo : uEhi) + b * NPP + strip0 + col;

    // prefetch first iteration
    u32x4v ba = {bp[0],  bp[2],  bp[4],  bp[6]};
    u32x4v bb = {bp[16], bp[18], bp[20], bp[22]};
    for (int s = 0; s < nsteps; s += 2) {
        // prefetch next iteration (pad in uE keeps this in-bounds)
        u32x4v na = {bp[32], bp[34], bp[36], bp[38]};
        u32x4v nb = {bp[48], bp[50], bp[52], bp[54]};
        bf16x8 Bav = __builtin_bit_cast(bf16x8, ba);
        bf16x8 Bbv = __builtin_bit_cast(bf16x8, bb);
        f32x4 d0 = __builtin_amdgcn_mfma_f32_16x16x32_bf16(aw0, Bav, Z, 0, 0, 0);
        f32x4 d1 = __builtin_amdgcn_mfma_f32_16x16x32_bf16(aw1, Bav, Z, 0, 0, 0);
        f32x4 d2 = __builtin_amdgcn_mfma_f32_16x16x32_bf16(aw2, Bav, Z, 0, 0, 0);
        f32x4 d3 = __builtin_amdgcn_mfma_f32_16x16x32_bf16(aw3, Bav, Z, 0, 0, 0);
        f32x4 d4 = __builtin_amdgcn_mfma_f32_16x16x32_bf16(aw4, Bav, Z, 0, 0, 0);
        #pragma unroll
        for (int r = 0; r < 4; ++r) {
            rm0[r] = fmaxf(rm0[r], d0[r]);
            rm1[r] = fmaxf(rm1[r], d1[r]);
            rm2[r] = fmaxf(rm2[r], d2[r]);
            rm3[r] = fmaxf(rm3[r], d3[r]);
            rm4[r] = fmaxf(rm4[r], d4[r]);
        }
        d0 = __builtin_amdgcn_mfma_f32_16x16x32_bf16(aw0, Bbv, Z, 0, 0, 0);
        d1 = __builtin_amdgcn_mfma_f32_16x16x32_bf16(aw1, Bbv, Z, 0, 0, 0);
        d2 = __builtin_amdgcn_mfma_f32_16x16x32_bf16(aw2, Bbv, Z, 0, 0, 0);
        d3 = __builtin_amdgcn_mfma_f32_16x16x32_bf16(aw3, Bbv, Z, 0, 0, 0);
        d4 = __builtin_amdgcn_mfma_f32_16x16x32_bf16(aw4, Bbv, Z, 0, 0, 0);
        #pragma unroll
        for (int r = 0; r < 4; ++r) {
            rm0[r] = fmaxf(rm0[r], d0[r]);
            rm1[r] = fmaxf(rm1[r], d1[r]);
            rm2[r] = fmaxf(rm2[r], d2[r]);
            rm3[r] = fmaxf(rm3[r], d3[r]);
            rm4[r] = fmaxf(rm4[r], d4[r]);
        }
        ba = na; bb = nb;
        bp += 32;
    }

    // ---- reduce over 16 position-cols, then atomic merge (f_local = q*4 + r) ----
    f32x4 rms[5] = {rm0, rm1, rm2, rm3, rm4};
    #pragma unroll
    for (int t = 0; t < 5; ++t) {
        #pragma unroll
        for (int r = 0; r < 4; ++r) {
            float v = rms[t][r];
            v = fmaxf(v, __shfl_xor(v, 1));
            v = fmaxf(v, __shfl_xor(v, 2));
            v = fmaxf(v, __shfl_xor(v, 4));
            v = fmaxf(v, __shfl_xor(v, 8));
            if (col == 0) {
                int f = (5 * wid + t) * 16 + q * 4 + r;   // C/D: row=(lane>>4)*4+reg
                atomicMax(&maxkey[b * NFPAD + f], monokey(v));
            }
        }
    }
}

// ---------------------------------------------------------------------------
// FC heads: decode keys -> relu(max + bias) -> 5 small matvecs. grid(NB), 128 thr
// ---------------------------------------------------------------------------
__global__ __launch_bounds__(128) void fc_kernel(
    const unsigned* __restrict__ maxkey,
    const float* __restrict__ cb1, const float* __restrict__ cb2, const float* __restrict__ cb3,
    const float* __restrict__ fw1, const float* __restrict__ fb1,
    const float* __restrict__ fw2, const float* __restrict__ fb2,
    const float* __restrict__ fw3, const float* __restrict__ fb3,
    const float* __restrict__ fw4, const float* __restrict__ fb4,
    const float* __restrict__ fw5, const float* __restrict__ fb5,
    float* __restrict__ out)   // [360] flat: 136 + 16 + 12 + 176 + 20
{
    __shared__ __align__(16) float feats[WDIM];
    const int b   = blockIdx.x;
    const int tid = threadIdx.x;

    for (int f = tid; f < WDIM; f += 128) {
        unsigned k = maxkey[b * NFPAD + f];
        unsigned u = (k & 0x80000000u) ? (k ^ 0x80000000u) : ~k;
        float y = __uint_as_float(u);
        float bias = (f < 100) ? cb1[f] : (f < 200) ? cb2[f - 100] : cb3[f - 200];
        feats[f] = fmaxf(0.f, y + bias);
    }
    __syncthreads();

    if (tid >= 90) return;
    const float* Wh; const float* Bh; int dim, off, j;
    int n = tid;
    if      (n < 34) { Wh = fw1; Bh = fb1; dim = 34; off = 0;   j = n;      }
    else if (n < 38) { Wh = fw2; Bh = fb2; dim = 4;  off = 136; j = n - 34; }
    else if (n < 41) { Wh = fw3; Bh = fb3; dim = 3;  off = 152; j = n - 38; }
    else if (n < 85) { Wh = fw4; Bh = fb4; dim = 44; off = 164; j = n - 41; }
    else             { Wh = fw5; Bh = fb5; dim = 5;  off = 340; j = n - 85; }

    float acc = Bh[j];
    const float* wr = Wh + j * WDIM;
    #pragma unroll 5
    for (int k = 0; k < WDIM; k += 4) {
        float4 wv = *reinterpret_cast<const float4*>(wr + k);
        acc = fmaf(wv.x, feats[k + 0], acc);
        acc = fmaf(wv.y, feats[k + 1], acc);
        acc = fmaf(wv.z, feats[k + 2], acc);
        acc = fmaf(wv.w, feats[k + 3], acc);
    }
    out[off + b * dim + j] = acc;
}

// ---------------------------------------------------------------------------
extern "C" void kernel_launch(void* const* d_in, const int* in_sizes, int n_in,
                              void* d_out, int out_size, void* d_ws, size_t ws_size,
                              hipStream_t stream) {
    const int*   x    = (const int*)  d_in[0];
    const float* emb  = (const float*)d_in[1];
    const float* w1   = (const float*)d_in[2];
    const float* b1   = (const float*)d_in[3];
    const float* w2   = (const float*)d_in[4];
    const float* b2   = (const float*)d_in[5];
    const float* w3   = (const float*)d_in[6];
    const float* b3   = (const float*)d_in[7];
    const float* fw1  = (const float*)d_in[8];
    const float* fb1  = (const float*)d_in[9];
    const float* fw2  = (const float*)d_in[10];
    const float* fb2  = (const float*)d_in[11];
    const float* fw3  = (const float*)d_in[12];
    const float* fb3  = (const float*)d_in[13];
    const float* fw4  = (const float*)d_in[14];
    const float* fb4  = (const float*)d_in[15];
    const float* fw5  = (const float*)d_in[16];
    const float* fb5  = (const float*)d_in[17];
    float* out = (float*)d_out;

    // ws layout (27.5 MiB): maxkey[1280] | uEhi[NB*NPP] | uElo[NB*NPP] | wsplit[5120 u16]
    unsigned*       maxkey = (unsigned*)d_ws;
    unsigned*       uEhi   = maxkey + NB * NFPAD;
    unsigned*       uElo   = uEhi + NB * NPP;
    unsigned short* wsplit = (unsigned short*)(uElo + NB * NPP);

    dim3 pgrid((NPP + NT - 1) / NT, NB);
    pack_kernel<<<pgrid, NT, 0, stream>>>(x, emb, w1, w2, w3,
                                          uEhi, uElo, wsplit, maxkey);

    dim3 cgrid(NSTRIPS + 1, NB);
    conv_mfma_kernel<<<cgrid, NT, 0, stream>>>(x, emb, w1, w2, w3,
                                               uEhi, uElo, wsplit, maxkey);

    fc_kernel<<<NB, 128, 0, stream>>>(maxkey, b1, b2, b3,
                                      fw1, fb1, fw2, fb2, fw3, fb3,
                                      fw4, fb4, fw5, fb5, out);
}

// Round 10
// 188.863 us; speedup vs baseline: 1.3584x; 1.3584x over previous
//
#include <hip/hip_runtime.h>
#include <stdint.h>

// Problem constants
#define L_SEQ   900000          // 3000 words * 300 dims
#define N_WORDS 3000
#define WDIM    300
#define NB      4               // batch
#define NFPAD   320             // filters padded to 20 MFMA tiles of 16
#define NT      256             // threads per block (4 waves; wave w owns tiles 5w..5w+4)
#define STRIP   2048            // positions per block = 128 steps of 16
#define STEPS   128
#define NSTG    2088            // packed pair entries (2048 + 40 pad for prefetch overrun)
#define NSTRIPS 440             // ceil(899968/2048); last strip partial (56 steps)
#define L_MAIN  899968          // conv kernel covers t in [0, L_MAIN); fc does the tail

typedef __attribute__((ext_vector_type(8))) short    bf16x8;
typedef __attribute__((ext_vector_type(4))) float    f32x4;
typedef __attribute__((ext_vector_type(4))) unsigned u32x4v;

__device__ __forceinline__ unsigned bf16rne(float v) {
    unsigned b = __float_as_uint(v);
    return (b + 0x7FFFu + ((b >> 16) & 1u)) >> 16;   // bf16 RNE, as ushort
}
// pack two f32 -> {bf16(a) lo16, bf16(b) hi16} (RNE) — no builtin on gfx950
__device__ __forceinline__ unsigned cvt_pk_bf16(float a, float b) {
    unsigned r;
    asm("v_cvt_pk_bf16_f32 %0, %1, %2" : "=v"(r) : "v"(a), "v"(b));
    return r;
}
__device__ __forceinline__ float gatherE(const int* __restrict__ x,
                                         const float* __restrict__ emb,
                                         int b, int pos) {
    if (pos >= L_SEQ) return 0.f;
    int wd = pos / WDIM;                  // constant divisor -> magic mul
    int d  = pos - wd * WDIM;
    return emb[x[b * N_WORDS + wd] * WDIM + d];
}

// ---------------------------------------------------------------------------
// Fused gather + full-split-in-K MFMA conv + running max -> per-strip partials.
// One mfma_f32_16x16x32_bf16 per (16 filters x 16 positions) step:
//   A quarters (k-groups) = {Whi, Wlo, Whi, Wlo}
//   B quarters            = {Ehi, Ehi, Elo, Elo}   (full 4-term split product)
// E split: hi = trunc16(v), lo = bf16rne(v - hi).
// No atomics, no memset dependency: block (bx,b) writes partial[b][bx][0..319].
// grid (NSTRIPS, NB) x 256.
// ---------------------------------------------------------------------------
__global__ __launch_bounds__(NT, 4) void conv_mfma_kernel(
    const int*   __restrict__ x,    // [4,3000]
    const float* __restrict__ emb,  // [VOCAB,300]
    const float* __restrict__ w1, const float* __restrict__ w2, const float* __restrict__ w3,
    float*       __restrict__ partial)  // [NB][NSTRIPS][NFPAD]
{
    __shared__ __align__(16) unsigned uH[NSTG];   // {hi(E[p]), hi(E[p+1])}
    __shared__ __align__(16) unsigned uL[NSTG];   // {lo(E[p]), lo(E[p+1])}

    const int tid    = threadIdx.x;
    const int b      = blockIdx.y;
    const int bx     = blockIdx.x;
    const int strip0 = bx * STRIP;

    // ---- staging, ONE sync: thread t packs pair-entries p = 8t .. 8t+7 ----
    {
        const int p0 = strip0 + tid * 8;
        float e[9]; unsigned u[9]; float l[9];
        #pragma unroll
        for (int j = 0; j < 9; ++j) {
            e[j] = gatherE(x, emb, b, p0 + j);
            u[j] = __float_as_uint(e[j]);
            l[j] = e[j] - __uint_as_float(u[j] & 0xFFFF0000u);
        }
        unsigned hh[8], ll[8];
        #pragma unroll
        for (int i = 0; i < 8; ++i) {
            hh[i] = __builtin_amdgcn_perm(u[i + 1], u[i], 0x07060302u); // {hi_i, hi_i+1}
            ll[i] = cvt_pk_bf16(l[i], l[i + 1]);                        // {lo_i, lo_i+1}
        }
        *(u32x4v*)&uH[tid * 8]     = (u32x4v){hh[0], hh[1], hh[2], hh[3]};
        *(u32x4v*)&uH[tid * 8 + 4] = (u32x4v){hh[4], hh[5], hh[6], hh[7]};
        *(u32x4v*)&uL[tid * 8]     = (u32x4v){ll[0], ll[1], ll[2], ll[3]};
        *(u32x4v*)&uL[tid * 8 + 4] = (u32x4v){ll[4], ll[5], ll[6], ll[7]};
        if (tid < NSTG - STRIP) {   // 40 pad entries (covers prefetch overrun)
            int p = STRIP + tid;
            float a0 = gatherE(x, emb, b, strip0 + p);
            float a1 = gatherE(x, emb, b, strip0 + p + 1);
            unsigned ua0 = __float_as_uint(a0), ua1 = __float_as_uint(a1);
            uH[p] = __builtin_amdgcn_perm(ua1, ua0, 0x07060302u);
            uL[p] = cvt_pk_bf16(a0 - __uint_as_float(ua0 & 0xFFFF0000u),
                                a1 - __uint_as_float(ua1 & 0xFFFF0000u));
        }
    }

    // ---- A fragments straight from global (3.6 KB total, L1-hot; one-time) ----
    const int lane = tid & 63;
    const int wid  = tid >> 6;           // wave 0..3
    const int col  = lane & 15;
    const int q    = lane >> 4;          // k-group 0..3
    const int part = q & 1;              // 0: Whi, 1: Wlo
    bf16x8 aw0, aw1, aw2, aw3, aw4;
    {
        bf16x8* awp[5] = {&aw0, &aw1, &aw2, &aw3, &aw4};
        #pragma unroll
        for (int t = 0; t < 5; ++t) {
            int f = (5 * wid + t) * 16 + col;
            int K; const float* wp;
            if (f < 100)      { K = 3; wp = w1 + f * 3; }
            else if (f < 200) { K = 4; wp = w2 + (f - 100) * 4; }
            else              { K = 5; wp = w3 + (f - 200) * 5; }
            float wv[8];
            #pragma unroll
            for (int j = 0; j < 8; ++j) wv[j] = (f < 300 && j < K) ? wp[j] : 0.f;
            unsigned d[4];
            #pragma unroll
            for (int i = 0; i < 4; ++i) {
                float a = wv[2 * i], c = wv[2 * i + 1];
                unsigned rha = bf16rne(a), rhc = bf16rne(c);
                if (part == 0) {
                    d[i] = rha | (rhc << 16);
                } else {
                    float la = a - __uint_as_float(rha << 16);
                    float lc = c - __uint_as_float(rhc << 16);
                    d[i] = bf16rne(la) | (bf16rne(lc) << 16);
                }
            }
            *awp[t] = __builtin_bit_cast(bf16x8, (u32x4v){d[0], d[1], d[2], d[3]});
        }
    }
    __syncthreads();

    int nsteps = (L_MAIN - strip0) / 16;     // 128, or 56 for the last strip — even
    if (nsteps > STEPS) nsteps = STEPS;

    const f32x4 Z = {0.f, 0.f, 0.f, 0.f};
    f32x4 rm0 = {-1e30f, -1e30f, -1e30f, -1e30f}, rm1 = rm0, rm2 = rm0, rm3 = rm0, rm4 = rm0;

    // B source: lanes 0-31 hi plane, 32-63 lo plane (quarters {hi,hi,lo,lo})
    const unsigned* bp = ((lane >> 5) ? uL : uH) + col;
    u32x4v ba = {bp[0],  bp[2],  bp[4],  bp[6]};
    u32x4v bb = {bp[16], bp[18], bp[20], bp[22]};
    for (int s = 0; s < nsteps; s += 2) {
        u32x4v na = {bp[32], bp[34], bp[36], bp[38]};   // prefetch next iter
        u32x4v nb = {bp[48], bp[50], bp[52], bp[54]};
        bf16x8 Ba = __builtin_bit_cast(bf16x8, ba);
        bf16x8 Bb = __builtin_bit_cast(bf16x8, bb);
        f32x4 a0 = __builtin_amdgcn_mfma_f32_16x16x32_bf16(aw0, Ba, Z, 0, 0, 0);
        f32x4 a1 = __builtin_amdgcn_mfma_f32_16x16x32_bf16(aw1, Ba, Z, 0, 0, 0);
        f32x4 a2 = __builtin_amdgcn_mfma_f32_16x16x32_bf16(aw2, Ba, Z, 0, 0, 0);
        f32x4 a3 = __builtin_amdgcn_mfma_f32_16x16x32_bf16(aw3, Ba, Z, 0, 0, 0);
        f32x4 a4 = __builtin_amdgcn_mfma_f32_16x16x32_bf16(aw4, Ba, Z, 0, 0, 0);
        f32x4 c0 = __builtin_amdgcn_mfma_f32_16x16x32_bf16(aw0, Bb, Z, 0, 0, 0);
        f32x4 c1 = __builtin_amdgcn_mfma_f32_16x16x32_bf16(aw1, Bb, Z, 0, 0, 0);
        f32x4 c2 = __builtin_amdgcn_mfma_f32_16x16x32_bf16(aw2, Bb, Z, 0, 0, 0);
        f32x4 c3 = __builtin_amdgcn_mfma_f32_16x16x32_bf16(aw3, Bb, Z, 0, 0, 0);
        f32x4 c4 = __builtin_amdgcn_mfma_f32_16x16x32_bf16(aw4, Bb, Z, 0, 0, 0);
        #pragma unroll
        for (int r = 0; r < 4; ++r) {   // fmax(fmax(x,y),z) -> v_max3_f32
            rm0[r] = fmaxf(fmaxf(rm0[r], a0[r]), c0[r]);
            rm1[r] = fmaxf(fmaxf(rm1[r], a1[r]), c1[r]);
            rm2[r] = fmaxf(fmaxf(rm2[r], a2[r]), c2[r]);
            rm3[r] = fmaxf(fmaxf(rm3[r], a3[r]), c3[r]);
            rm4[r] = fmaxf(fmaxf(rm4[r], a4[r]), c4[r]);
        }
        ba = na; bb = nb;
        bp += 32;
    }

    // ---- reduce over 16 position-cols, store per-strip partials (no atomics) ----
    float* pout = partial + ((size_t)b * NSTRIPS + bx) * NFPAD;
    f32x4 rms[5] = {rm0, rm1, rm2, rm3, rm4};
    #pragma unroll
    for (int t = 0; t < 5; ++t) {
        #pragma unroll
        for (int r = 0; r < 4; ++r) {
            float v = rms[t][r];
            v = fmaxf(v, __shfl_xor(v, 1));
            v = fmaxf(v, __shfl_xor(v, 2));
            v = fmaxf(v, __shfl_xor(v, 4));
            v = fmaxf(v, __shfl_xor(v, 8));
            if (col == 0) {
                int f = (5 * wid + t) * 16 + q * 4 + r;   // C/D: row=(lane>>4)*4+reg
                pout[f] = v;
            }
        }
    }
}

// ---------------------------------------------------------------------------
// FC: reduce partials over strips + exact fp32 tail + relu(max+bias) + 5 heads.
// grid (NB) x 320.
// ---------------------------------------------------------------------------
__global__ __launch_bounds__(320) void fc_kernel(
    const float* __restrict__ partial,
    const int*   __restrict__ x, const float* __restrict__ emb,
    const float* __restrict__ w1, const float* __restrict__ w2, const float* __restrict__ w3,
    const float* __restrict__ cb1, const float* __restrict__ cb2, const float* __restrict__ cb3,
    const float* __restrict__ fw1, const float* __restrict__ fb1,
    const float* __restrict__ fw2, const float* __restrict__ fb2,
    const float* __restrict__ fw3, const float* __restrict__ fb3,
    const float* __restrict__ fw4, const float* __restrict__ fb4,
    const float* __restrict__ fw5, const float* __restrict__ fb5,
    float* __restrict__ out)   // [360] flat: 136 + 16 + 12 + 176 + 20
{
    __shared__ float tE[40];
    __shared__ __align__(16) float feats[NFPAD];
    const int b   = blockIdx.x;
    const int tid = threadIdx.x;

    if (tid < 40) tE[tid] = gatherE(x, emb, b, L_MAIN + tid);
    __syncthreads();

    if (tid < 300) {
        // reduce per-strip partials (4 independent chains to pipeline loads)
        const float* pp = partial + (size_t)b * NSTRIPS * NFPAD + tid;
        float m0 = -1e30f, m1 = m0, m2 = m0, m3 = m0;
        for (int s = 0; s < NSTRIPS; s += 4) {        // 440 % 4 == 0
            m0 = fmaxf(m0, pp[(s + 0) * NFPAD]);
            m1 = fmaxf(m1, pp[(s + 1) * NFPAD]);
            m2 = fmaxf(m2, pp[(s + 2) * NFPAD]);
            m3 = fmaxf(m3, pp[(s + 3) * NFPAD]);
        }
        float m = fmaxf(fmaxf(m0, m1), fmaxf(m2, m3));

        // exact fp32 tail: window starts t in [L_MAIN, L_SEQ-K]
        int f = tid, K; const float* wp; float bias;
        if (f < 100)      { K = 3; wp = w1 + f * 3;         bias = cb1[f]; }
        else if (f < 200) { K = 4; wp = w2 + (f - 100) * 4; bias = cb2[f - 100]; }
        else              { K = 5; wp = w3 + (f - 200) * 5; bias = cb3[f - 200]; }
        float wk0 = wp[0], wk1 = wp[1], wk2 = (K > 2) ? wp[2] : 0.f;
        float wk3 = (K > 3) ? wp[3] : 0.f, wk4 = (K > 4) ? wp[4] : 0.f;
        for (int t = 0; t <= 32 - K; ++t) {
            float y = wk0 * tE[t] + wk1 * tE[t + 1] + wk2 * tE[t + 2]
                    + wk3 * tE[t + 3] + wk4 * tE[t + 4];
            m = fmaxf(m, y);
        }
        feats[f] = fmaxf(0.f, m + bias);
    }
    __syncthreads();

    if (tid >= 90) return;
    const float* Wh; const float* Bh; int dim, off, j;
    int n = tid;
    if      (n < 34) { Wh = fw1; Bh = fb1; dim = 34; off = 0;   j = n;      }
    else if (n < 38) { Wh = fw2; Bh = fb2; dim = 4;  off = 136; j = n - 34; }
    else if (n < 41) { Wh = fw3; Bh = fb3; dim = 3;  off = 152; j = n - 38; }
    else if (n < 85) { Wh = fw4; Bh = fb4; dim = 44; off = 164; j = n - 41; }
    else             { Wh = fw5; Bh = fb5; dim = 5;  off = 340; j = n - 85; }

    float acc = Bh[j];
    const float* wr = Wh + j * WDIM;
    #pragma unroll 5
    for (int k = 0; k < WDIM; k += 4) {
        float4 wv = *reinterpret_cast<const float4*>(wr + k);
        acc = fmaf(wv.x, feats[k + 0], acc);
        acc = fmaf(wv.y, feats[k + 1], acc);
        acc = fmaf(wv.z, feats[k + 2], acc);
        acc = fmaf(wv.w, feats[k + 3], acc);
    }
    out[off + b * dim + j] = acc;
}

// ---------------------------------------------------------------------------
extern "C" void kernel_launch(void* const* d_in, const int* in_sizes, int n_in,
                              void* d_out, int out_size, void* d_ws, size_t ws_size,
                              hipStream_t stream) {
    const int*   x    = (const int*)  d_in[0];
    const float* emb  = (const float*)d_in[1];
    const float* w1   = (const float*)d_in[2];
    const float* b1   = (const float*)d_in[3];
    const float* w2   = (const float*)d_in[4];
    const float* b2   = (const float*)d_in[5];
    const float* w3   = (const float*)d_in[6];
    const float* b3   = (const float*)d_in[7];
    const float* fw1  = (const float*)d_in[8];
    const float* fb1  = (const float*)d_in[9];
    const float* fw2  = (const float*)d_in[10];
    const float* fb2  = (const float*)d_in[11];
    const float* fw3  = (const float*)d_in[12];
    const float* fb3  = (const float*)d_in[13];
    const float* fw4  = (const float*)d_in[14];
    const float* fb4  = (const float*)d_in[15];
    const float* fw5  = (const float*)d_in[16];
    const float* fb5  = (const float*)d_in[17];
    float* out     = (float*)d_out;
    float* partial = (float*)d_ws;     // [NB][NSTRIPS][NFPAD] = 2.25 MB

    dim3 cgrid(NSTRIPS, NB);
    conv_mfma_kernel<<<cgrid, NT, 0, stream>>>(x, emb, w1, w2, w3, partial);

    fc_kernel<<<NB, 320, 0, stream>>>(partial, x, emb, w1, w2, w3, b1, b2, b3,
                                      fw1, fb1, fw2, fb2, fw3, fb3,
                                      fw4, fb4, fw5, fb5, out);
}